// Round 6
// baseline (573.176 us; speedup 1.0000x reference)
//
#include <hip/hip_runtime.h>
#include <hip/hip_bf16.h>
#include <math.h>

#define B_ 2
#define T_ 2048
#define D_ 2048
#define H_ 16
#define DH_ 128
#define SEM_ 1024
#define GEO_ 1024
#define NPROJ 6144   // 4*1024 (q/k sem/geo) + 2048 (v)

typedef unsigned short ushort_t;
typedef short bf16x8 __attribute__((ext_vector_type(8)));
typedef float f32x4 __attribute__((ext_vector_type(4)));

static __device__ inline ushort_t f2b(float x) {
    __hip_bfloat16 h = __float2bfloat16(x);
    return *reinterpret_cast<ushort_t*>(&h);
}
static __device__ inline float b2f(ushort_t u) {
    union { unsigned int i; float f; } v; v.i = ((unsigned int)u) << 16; return v.f;
}
static __device__ inline void gload_lds16(const ushort_t* g, ushort_t* l) {
    __builtin_amdgcn_global_load_lds(
        (const __attribute__((address_space(1))) void*)g,
        (__attribute__((address_space(3))) void*)l, 16, 0, 0);
}

// ---------------------------------------------------------------------------
// x fp32 -> bf16, 8 elems/thread
// ---------------------------------------------------------------------------
__global__ __launch_bounds__(256) void convert_x(
    const float* __restrict__ x, ushort_t* __restrict__ xh)
{
    size_t i = ((size_t)blockIdx.x * 256 + threadIdx.x) * 8;
    float4 a = *(const float4*)&x[i];
    float4 b = *(const float4*)&x[i + 4];
    bf16x8 o;
    o[0] = (short)f2b(a.x); o[1] = (short)f2b(a.y);
    o[2] = (short)f2b(a.z); o[3] = (short)f2b(a.w);
    o[4] = (short)f2b(b.x); o[5] = (short)f2b(b.y);
    o[6] = (short)f2b(b.z); o[7] = (short)f2b(b.w);
    *(bf16x8*)&xh[i] = o;
}

// ---------------------------------------------------------------------------
// All 6 weight transposes in one launch. z selects the weight.
// W[K=2048][N] fp32 -> dst[N][2048] bf16.
// ---------------------------------------------------------------------------
__global__ __launch_bounds__(256) void transpose_all(
    const float* __restrict__ W0, const float* __restrict__ W1,
    const float* __restrict__ W2, const float* __restrict__ W3,
    const float* __restrict__ W4, const float* __restrict__ W5,
    ushort_t* __restrict__ Wt_all, ushort_t* __restrict__ WoT)
{
    const int z = blockIdx.z;
    const float* W;
    ushort_t* dst;
    int N;
    switch (z) {
        case 0: W = W0; dst = Wt_all;                          N = 1024; break;
        case 1: W = W1; dst = Wt_all + (size_t)1024 * 2048;    N = 1024; break;
        case 2: W = W2; dst = Wt_all + (size_t)2048 * 2048;    N = 1024; break;
        case 3: W = W3; dst = Wt_all + (size_t)3072 * 2048;    N = 1024; break;
        case 4: W = W4; dst = Wt_all + (size_t)4096 * 2048;    N = 2048; break;
        default: W = W5; dst = WoT;                            N = 2048; break;
    }
    const int n0 = blockIdx.x * 32;
    if (n0 >= N) return;
    const int k0 = blockIdx.y * 32;

    __shared__ float tile[32][33];
    const int c = threadIdx.x & 31, r = threadIdx.x >> 5;   // r: 0..7
#pragma unroll
    for (int rr = 0; rr < 32; rr += 8)
        tile[r + rr][c] = W[(size_t)(k0 + r + rr) * N + n0 + c];
    __syncthreads();
#pragma unroll
    for (int rr = 0; rr < 32; rr += 8)
        dst[(size_t)(n0 + r + rr) * 2048 + k0 + c] = f2b(tile[c][r + rr]);
}

// ---------------------------------------------------------------------------
// Projection GEMM with fused RoPE/gate/pack epilogue.
// C-tile cols map to: [0,1024) qs | [1024,2048) ks | [2048,3072) qg |
// [3072,4096) kg | [4096,6144) v.  Writes Qh/Kh [bh][t][128], Vt [bh][d][t].
// RoPE pair (i, i+32) = lane regs (j, j+2); head is wave-uniform.
// ---------------------------------------------------------------------------
__global__ __launch_bounds__(256) void gemm_proj(
    const ushort_t* __restrict__ A, const ushort_t* __restrict__ Bt,
    const float* __restrict__ gate_logit, const int* __restrict__ pos_off,
    ushort_t* __restrict__ Qh, ushort_t* __restrict__ Kh,
    ushort_t* __restrict__ Vt)
{
    const int K = 2048;
    __shared__ ushort_t As[128 * 32];
    __shared__ ushort_t Bs[128 * 32];

    const int tid  = threadIdx.x;
    const int wid  = tid >> 6, lane = tid & 63;
    const int ln16 = lane & 15, g = lane >> 4;
    const int wm = wid & 1, wn = wid >> 1;
    const int m0 = blockIdx.y * 128, n0 = blockIdx.x * 128;

    const int lrow = lane >> 2;
    const int lc8  = (lane & 3) * 8;
    const ushort_t* gA = A  + (size_t)(m0 + wid * 32 + lrow) * K + lc8;
    const ushort_t* gB = Bt + (size_t)(n0 + wid * 32 + lrow) * K + lc8;
    ushort_t* lA = As + wid * 1024;
    ushort_t* lB = Bs + wid * 1024;
    const size_t K16 = (size_t)16 * K;

    f32x4 acc[4][4];
#pragma unroll
    for (int i = 0; i < 4; ++i)
#pragma unroll
        for (int j = 0; j < 4; ++j) acc[i][j] = (f32x4){0.f, 0.f, 0.f, 0.f};

    for (int k0 = 0; k0 < K; k0 += 32) {
        __syncthreads();
        gload_lds16(gA,       lA);
        gload_lds16(gA + K16, lA + 512);
        gload_lds16(gB,       lB);
        gload_lds16(gB + K16, lB + 512);
        gA += 32; gB += 32;
        __syncthreads();

        bf16x8 af[4], bfr[4];
#pragma unroll
        for (int i = 0; i < 4; ++i)
            af[i] = *(const bf16x8*)&As[(wm * 64 + i * 16 + ln16) * 32 + g * 8];
#pragma unroll
        for (int j = 0; j < 4; ++j)
            bfr[j] = *(const bf16x8*)&Bs[(wn * 64 + j * 16 + ln16) * 32 + g * 8];
#pragma unroll
        for (int i = 0; i < 4; ++i)
#pragma unroll
            for (int j = 0; j < 4; ++j)
                acc[i][j] = __builtin_amdgcn_mfma_f32_16x16x32_bf16(
                    af[i], bfr[j], acc[i][j], 0, 0, 0);
    }

    // ---- fused epilogue. row = m0 + wm*64 + i*16 + g*4 + r -> (b, t)
    const int region = n0 >> 10;           // 0 qs | 1 ks | 2 qg | 3 kg | >=4 v
    const int rbase  = m0 + wm * 64 + g * 4;

    if (region <= 1) {
        const int h = ((n0 & 1023) >> 6) + wn;         // wave-uniform
        ushort_t* dst = (region == 0) ? Qh : Kh;
        float sc = 1.0f;
        if (region == 0) {
            float sg = 1.0f / (1.0f + __expf(-gate_logit[h]));
            sc = 0.25f * sg;                            // 2*sigma*0.125
        }
#pragma unroll
        for (int i = 0; i < 4; ++i)
#pragma unroll
            for (int r = 0; r < 4; ++r) {
                int row = rbase + i * 16 + r;
                int t = row & (T_ - 1), bb = row >> 11;
                size_t base = ((size_t)(bb * H_ + h) * T_ + t) * 128;
#pragma unroll
                for (int j = 0; j < 4; ++j)
                    dst[base + j * 16 + ln16] = f2b(acc[i][j][r] * sc);
            }
    } else if (region <= 3) {
        const int h = ((n0 & 1023) >> 6) + wn;
        ushort_t* dst = (region == 2) ? Qh : Kh;
        float sc = 1.0f;
        if (region == 2) {
            float sg = 1.0f / (1.0f + __expf(-gate_logit[h]));
            sc = 0.25f * (1.0f - sg);                   // (2-2*sigma)*0.125
        }
        const float po = (float)(*pos_off);
#pragma unroll
        for (int j = 0; j < 2; ++j) {
            const int ip = j * 16 + ln16;               // rope pair index 0..31
            const float invf = __expf(-0.28782313665087625f * (float)ip);
#pragma unroll
            for (int i = 0; i < 4; ++i)
#pragma unroll
                for (int r = 0; r < 4; ++r) {
                    int row = rbase + i * 16 + r;
                    int t = row & (T_ - 1), bb = row >> 11;
                    float s, c;
                    __sincosf(((float)t + po) * invf, &s, &c);
                    float x1 = acc[i][j][r], x2 = acc[i][j + 2][r];
                    size_t base = ((size_t)(bb * H_ + h) * T_ + t) * 128;
                    dst[base + 64 + ip] = f2b((x1 * c - x2 * s) * sc);
                    dst[base + 96 + ip] = f2b((x2 * c + x1 * s) * sc);
                }
        }
    } else {
        const int h = (n0 - 4096) >> 7;                 // block-uniform
#pragma unroll
        for (int j = 0; j < 4; ++j) {
            const int d = wn * 64 + j * 16 + ln16;      // 0..127
#pragma unroll
            for (int i = 0; i < 4; ++i)
#pragma unroll
                for (int r = 0; r < 4; ++r) {
                    int row = rbase + i * 16 + r;
                    int t = row & (T_ - 1), bb = row >> 11;
                    Vt[((size_t)(bb * H_ + h) * DH_ + d) * T_ + t] =
                        f2b(acc[i][j][r]);
                }
        }
    }
}

// ---------------------------------------------------------------------------
// Generic bf16 MFMA GEMM (m97 structure), fp32 out — used for Wo.
// ---------------------------------------------------------------------------
__global__ __launch_bounds__(256) void gemm_bt_f32(
    const ushort_t* __restrict__ A, const ushort_t* __restrict__ Bt,
    float* __restrict__ C, int M, int N, int K)
{
    __shared__ ushort_t As[128 * 32];
    __shared__ ushort_t Bs[128 * 32];

    const int tid  = threadIdx.x;
    const int wid  = tid >> 6, lane = tid & 63;
    const int ln16 = lane & 15, g = lane >> 4;
    const int wm = wid & 1, wn = wid >> 1;
    const int m0 = blockIdx.y * 128, n0 = blockIdx.x * 128;

    const int lrow = lane >> 2;
    const int lc8  = (lane & 3) * 8;
    const ushort_t* gA = A  + (size_t)(m0 + wid * 32 + lrow) * K + lc8;
    const ushort_t* gB = Bt + (size_t)(n0 + wid * 32 + lrow) * K + lc8;
    ushort_t* lA = As + wid * 1024;
    ushort_t* lB = Bs + wid * 1024;
    const size_t K16 = (size_t)16 * K;

    f32x4 acc[4][4];
#pragma unroll
    for (int i = 0; i < 4; ++i)
#pragma unroll
        for (int j = 0; j < 4; ++j) acc[i][j] = (f32x4){0.f, 0.f, 0.f, 0.f};

    for (int k0 = 0; k0 < K; k0 += 32) {
        __syncthreads();
        gload_lds16(gA,       lA);
        gload_lds16(gA + K16, lA + 512);
        gload_lds16(gB,       lB);
        gload_lds16(gB + K16, lB + 512);
        gA += 32; gB += 32;
        __syncthreads();

        bf16x8 af[4], bfr[4];
#pragma unroll
        for (int i = 0; i < 4; ++i)
            af[i] = *(const bf16x8*)&As[(wm * 64 + i * 16 + ln16) * 32 + g * 8];
#pragma unroll
        for (int j = 0; j < 4; ++j)
            bfr[j] = *(const bf16x8*)&Bs[(wn * 64 + j * 16 + ln16) * 32 + g * 8];
#pragma unroll
        for (int i = 0; i < 4; ++i)
#pragma unroll
            for (int j = 0; j < 4; ++j)
                acc[i][j] = __builtin_amdgcn_mfma_f32_16x16x32_bf16(
                    af[i], bfr[j], acc[i][j], 0, 0, 0);
    }

#pragma unroll
    for (int i = 0; i < 4; ++i)
#pragma unroll
        for (int j = 0; j < 4; ++j)
#pragma unroll
            for (int r = 0; r < 4; ++r) {
                int row = m0 + wm * 64 + i * 16 + g * 4 + r;
                int col = n0 + wn * 64 + j * 16 + ln16;
                C[(size_t)row * N + col] = acc[i][j][r];
            }
}

// ---------------------------------------------------------------------------
// Flash attention v4 — barrier-free streaming:
//  - NO K/V LDS staging: MFMA B-fragments loaded directly from global
//    (b128 per lane; L1 serves intra-block reuse, L2 inter-block)
//  - zero __syncthreads: each wave runs to its own exact trip count
//  - balanced pairing (block p does q-tiles p and 31-p), static-max softmax,
//    ones-column row-sum (unchanged from v2/v3)
// ---------------------------------------------------------------------------
#define P_PITCH  40

__global__ __launch_bounds__(256) void flash_attn(
    const ushort_t* __restrict__ Qh,
    const ushort_t* __restrict__ Kh,
    const ushort_t* __restrict__ Vt,     // [bh][128][T]
    ushort_t* __restrict__ aoh)          // [b*T+t][2048] bf16
{
    __shared__ ushort_t Pl[4 * 16 * P_PITCH];

    const int tid  = threadIdx.x;
    const int wid  = tid >> 6, lane = tid & 63;
    const int ln16 = lane & 15, g = lane >> 4;
    const int p    = blockIdx.x;         // pair index 0..15
    const int h  = blockIdx.y, b = blockIdx.z;
    const int bh = b * H_ + h;

    const ushort_t* Kbase = Kh + (size_t)bh * T_ * 128;
    const ushort_t* Vbase = Vt + (size_t)bh * 128 * T_;
    ushort_t* Pw = Pl + wid * 16 * P_PITCH;

    // ones B-fragment: B[0][k] = 1, else 0  (row-sum accumulator)
    bf16x8 bones;
    {
        short o = (ln16 == 0) ? (short)0x3F80 : (short)0;
#pragma unroll
        for (int j = 0; j < 8; ++j) bones[j] = o;
    }

#pragma unroll 1
    for (int ti = 0; ti < 2; ++ti) {
        const int qt = ti ? (31 - p) : p;
        const int q0 = qt * 64;
        const int qw = q0 + wid * 16;

        bf16x8 aq[4];
        {
            const ushort_t* qrow = Qh + ((size_t)bh * T_ + qw + ln16) * 128;
#pragma unroll
            for (int c2 = 0; c2 < 4; ++c2)
                aq[c2] = *(const bf16x8*)(qrow + c2 * 32 + g * 8);
        }

        f32x4 acc[8];
#pragma unroll
        for (int i = 0; i < 8; ++i) acc[i] = (f32x4){0.f, 0.f, 0.f, 0.f};
        f32x4 acc_l = (f32x4){0.f, 0.f, 0.f, 0.f};

        const int qmax = qw + 15;
        const int nkb  = qmax / 32 + 1;     // per-wave exact trip count

        for (int kb = 0; kb < nkb; ++kb) {
            const int kt = kb * 32;
            const ushort_t* Kt = Kbase + (size_t)kt * 128;
            const ushort_t* Vk = Vbase + kt;

            // ---- QK^T: B-frags straight from global (b128, L1/L2-served)
            f32x4 s0 = (f32x4){0.f, 0.f, 0.f, 0.f};
            f32x4 s1 = (f32x4){0.f, 0.f, 0.f, 0.f};
            bf16x8 bk0[4], bk1[4];
#pragma unroll
            for (int c2 = 0; c2 < 4; ++c2) {
                bk0[c2] = *(const bf16x8*)(Kt + (size_t)ln16 * 128        + c2 * 32 + g * 8);
                bk1[c2] = *(const bf16x8*)(Kt + (size_t)(16 + ln16) * 128 + c2 * 32 + g * 8);
            }
#pragma unroll
            for (int c2 = 0; c2 < 4; ++c2) {
                s0 = __builtin_amdgcn_mfma_f32_16x16x32_bf16(aq[c2], bk0[c2], s0, 0, 0, 0);
                s1 = __builtin_amdgcn_mfma_f32_16x16x32_bf16(aq[c2], bk1[c2], s1, 0, 0, 0);
            }

            // ---- static-max softmax, mask only on diagonal blocks
            const bool diag = (kt + 31 > qw);
#pragma unroll
            for (int r2 = 0; r2 < 4; ++r2) {
                float e0 = __expf(s0[r2] - 12.0f);
                float e1 = __expf(s1[r2] - 12.0f);
                if (diag) {
                    int qr = qw + g * 4 + r2;
                    e0 = (kt + ln16      > qr) ? 0.0f : e0;
                    e1 = (kt + 16 + ln16 > qr) ? 0.0f : e1;
                }
                int prow = g * 4 + r2;
                Pw[prow * P_PITCH + ln16]      = f2b(e0);
                Pw[prow * P_PITCH + 16 + ln16] = f2b(e1);
            }
            __asm__ volatile("s_waitcnt lgkmcnt(0)" ::: "memory");
            bf16x8 ap = *(const bf16x8*)&Pw[ln16 * P_PITCH + g * 8];

            // ---- PV: V B-frags straight from global + ones-column row-sum
#pragma unroll
            for (int cdv = 0; cdv < 8; ++cdv) {
                bf16x8 bv = *(const bf16x8*)
                    (Vk + (size_t)(cdv * 16 + ln16) * T_ + g * 8);
                acc[cdv] = __builtin_amdgcn_mfma_f32_16x16x32_bf16(ap, bv, acc[cdv], 0, 0, 0);
            }
            acc_l = __builtin_amdgcn_mfma_f32_16x16x32_bf16(ap, bones, acc_l, 0, 0, 0);
        }

        // ---- epilogue: broadcast l from ln16==0 lanes, normalize, store bf16
        float invl[4];
#pragma unroll
        for (int r2 = 0; r2 < 4; ++r2)
            invl[r2] = 1.0f / __shfl(acc_l[r2], lane & 48);
#pragma unroll
        for (int cdv = 0; cdv < 8; ++cdv)
#pragma unroll
            for (int r2 = 0; r2 < 4; ++r2) {
                int qr = qw + g * 4 + r2;
                aoh[((size_t)b * T_ + qr) * D_ + h * DH_ + cdv * 16 + ln16] =
                    f2b(acc[cdv][r2] * invl[r2]);
            }
    }
}

// ---------------------------------------------------------------------------
extern "C" void kernel_launch(void* const* d_in, const int* in_sizes, int n_in,
                              void* d_out, int out_size, void* d_ws, size_t ws_size,
                              hipStream_t stream)
{
    const float* x       = (const float*)d_in[0];
    const float* Wq_sem  = (const float*)d_in[1];
    const float* Wk_sem  = (const float*)d_in[2];
    const float* Wq_geo  = (const float*)d_in[3];
    const float* Wk_geo  = (const float*)d_in[4];
    const float* Wv      = (const float*)d_in[5];
    const float* Wo      = (const float*)d_in[6];
    const float* gate    = (const float*)d_in[7];
    const int*   pos_off = (const int*)d_in[8];
    float* out = (float*)d_out;

    const int M = B_ * T_;                       // 4096
    char* ws = (char*)d_ws;
    ushort_t* xh     = (ushort_t*)(ws);                          // [4096][2048] 16MB
    ushort_t* aoh    = xh;                                       // reuse after proj
    ushort_t* Wt_all = (ushort_t*)(ws + (size_t)16 * 1048576);   // [6144][2048] 24MB
    ushort_t* WoT    = (ushort_t*)(ws + (size_t)40 * 1048576);   // [2048][2048] 8MB
    ushort_t* Qh     = (ushort_t*)(ws + (size_t)48 * 1048576);   // 16MB
    ushort_t* Kh     = (ushort_t*)(ws + (size_t)64 * 1048576);   // 16MB
    ushort_t* Vt     = (ushort_t*)(ws + (size_t)80 * 1048576);   // 16MB

    dim3 blk(256);

    convert_x<<<(M * D_) / (256 * 8), blk, 0, stream>>>(x, xh);
    transpose_all<<<dim3(64, 64, 6), blk, 0, stream>>>(
        Wq_sem, Wk_sem, Wq_geo, Wk_geo, Wv, Wo, Wt_all, WoT);

    gemm_proj<<<dim3(NPROJ / 128, M / 128), blk, 0, stream>>>(
        xh, Wt_all, gate, pos_off, Qh, Kh, Vt);

    flash_attn<<<dim3(16, H_, B_), blk, 0, stream>>>(Qh, Kh, Vt, aoh);

    gemm_bt_f32<<<dim3(D_ / 128, M / 128), blk, 0, stream>>>(
        aoh, WoT, out, M, D_, D_);
}